// Round 11
// baseline (197.225 us; speedup 1.0000x reference)
//
#include <hip/hip_runtime.h>

// ---------------- problem constants ----------------
#define BATCH   8
#define LSEQ    1048576          // 1<<20
#define KCONV   500
#define TWIN    2097             // (L-K)/K + 1
#define MROWS   16776            // BATCH*TWIN
#define KDIM    4000             // KCONV * C_IN
#define NDIM    256              // 2 * C_OUT
#define COUT    128
#define VOCAB   257
#define VOCABP  256              // padding row of emb (zeros)

// 1049 m-tiles of 16 rows over 512 blocks: 487 x 2-tile + 25 x 3-tile.
// Grid 512 = 2 blocks/CU co-resident on all 256 CUs (4 waves/SIMD), no serial tail.
#define GRID    512
#define G2BLK   487              // blocks with 2 tiles; rest have 3
#define MAXT    3                // max m-tiles per block
#define MAXROWS (MAXT * 16)      // 48
#define SLABP   20               // positions per slab = 160 k = 5 BK32 iters
#define NSLAB   25
#define NG      125              // total BK32 iterations
#define PLANE   (NDIM * 32)      // 8192 shorts per g-plane of Wtf
#define AROWSH  168              // padded shorts per A-slab row (160 + 8)

// ---------------- ws layout (bytes) ----------------
#define WTF_OFF   0ull
#define WTF_BYTES ((size_t)NG * PLANE * 2)                  // 2,048,000
#define POOL_OFF  (WTF_OFF + WTF_BYTES)                     // 1024 floats

typedef __attribute__((ext_vector_type(8))) __bf16 bf16x8;
typedef __attribute__((ext_vector_type(4))) float  floatx4;

__device__ inline unsigned short f2bf(float f) {
    union { float f; unsigned u; } c; c.f = f;
    return (unsigned short)((c.u + 0x7FFFu + ((c.u >> 16) & 1u)) >> 16);
}
__device__ inline unsigned pack2(float lo, float hi) {
    return (unsigned)f2bf(lo) | ((unsigned)f2bf(hi) << 16);
}

// barrier that waits ONLY for LDS ops — leaves global (B/x prefetch) loads in flight
#define LDS_BARRIER() asm volatile("s_waitcnt lgkmcnt(0)\n\ts_barrier" ::: "memory")

// ---------------- kernel 1: frag-major weights + zero pool ----------------
// Wtf[g][n][kk] = w_n[e=(g*32+kk)&7][p=(g*32+kk)>>3]
__global__ __launch_bounds__(256) void wprep_kernel(const float* __restrict__ w1,
                                                    const float* __restrict__ w2,
                                                    unsigned short* __restrict__ Wtf,
                                                    float* __restrict__ pool) {
    const int n   = blockIdx.x;                        // 0..255
    const int tid = threadIdx.x;
    __shared__ float tile[KDIM];                       // 16 KB
    const float* src = (n < COUT) ? (w1 + (size_t)n * KDIM)
                                  : (w2 + (size_t)(n - COUT) * KDIM);
    for (int i = tid; i < KDIM; i += 256) tile[i] = src[i];
    __syncthreads();
    for (int i = tid; i < KDIM; i += 256) {
        int g = i >> 5, kk = i & 31;
        Wtf[(size_t)g * PLANE + n * 32 + kk] = f2bf(tile[(i & 7) * KCONV + (i >> 3)]);
    }
    if (n == 0 && tid < BATCH * COUT / 2)
        ((float2*)pool)[tid] = float2{0.f, 0.f};
}

// ---------------- kernel 2: fused embed + full-K GEMM + gate + max-pool ----------------
// 512 thr (8 waves). Wave wv, lane (r16,q): o = wv*16 + r16 (0..127);
// acc[i][0]=c1, acc[i][1]=c2 (n=o+128) -> gate fully in registers.
// A: LDS emb table (gathers via the 32-bank crossbar, not the L1/TA path — the
//    r3..r7 serializer). Slab double-buffered; compute-then-stage ordering.
// B: frag-major Wtf, coalesced 1KB register loads, depth-2 prefetch; LDS_BARRIER
//    (lgkm-only) never drains them. x prefetched a full slab ahead on vmcnt.
// nt (2 or 3 m-tiles) is wave-uniform per block -> guarded unrolled loops.
__global__ __launch_bounds__(512, 4) void gemm_kernel(const int* __restrict__ x,
                                                      const float* __restrict__ emb,
                                                      const unsigned short* __restrict__ Wtf,
                                                      const float* __restrict__ b1,
                                                      const float* __restrict__ b2,
                                                      float* __restrict__ pool) {
    __shared__ unsigned short tableL[VOCAB * 8];       // 4112 B
    __shared__ unsigned short As[2][MAXROWS * AROWSH]; // 2 x 15.75 KB

    const int tid  = threadIdx.x;
    const int lane = tid & 63;
    const int wv   = tid >> 6;                         // 0..7
    const int r16  = lane & 15;
    const int q    = lane >> 4;                        // 0..3

    const int bid  = blockIdx.x;
    int base, nt;
    if (bid < G2BLK) { base = 2 * bid;                nt = 2; }
    else             { base = 974 + 3 * (bid - G2BLK); nt = 3; }
    const int m0     = base * 16;
    const int stagen = nt * 16 * SLABP;                // 640 or 960

    // ---- build bf16 emb table in LDS ----
    if (tid < VOCAB) {
        const float4* er = (const float4*)(emb + tid * 8);
        float4 a = er[0], b = er[1];
        uint4 u;
        u.x = pack2(a.x, a.y); u.y = pack2(a.z, a.w);
        u.z = pack2(b.x, b.y); u.w = pack2(b.z, b.w);
        *(uint4*)(tableL + tid * 8) = u;
    }

    // ---- staging roles: thread handles idx = tid + 512*l (idx < stagen) ----
    const int* xptr[2];
    int        loff[2];
    bool       sval[2];
#pragma unroll
    for (int l = 0; l < 2; ++l) {
        int idx = tid + 512 * l;
        bool v  = (idx < stagen);
        int ic  = v ? idx : 0;
        int row = ic / SLABP;
        int pos = ic - row * SLABP;
        int am  = m0 + row;
        v = v && (am < MROWS);
        sval[l] = v;
        int amc = v ? am : 0;
        int b   = amc / TWIN;
        int t   = amc - b * TWIN;
        xptr[l] = x + ((size_t)b * LSEQ + (size_t)t * KCONV + pos);
        loff[l] = row * AROWSH + pos * 8;
    }

    // ---- compute role ----
    const int o = wv * 16 + r16;                       // 0..127
    const size_t boff0 = (size_t)o * 32 + q * 8;
    const size_t boff1 = (size_t)(o + 128) * 32 + q * 8;

    floatx4 acc[MAXT][2];
#pragma unroll
    for (int i = 0; i < MAXT; ++i) { acc[i][0] = floatx4{0,0,0,0}; acc[i][1] = floatx4{0,0,0,0}; }

    // ---- x values for slab 0 ----
    int xv[2], xn[2];
#pragma unroll
    for (int l = 0; l < 2; ++l) xv[l] = sval[l] ? xptr[l][0] : VOCABP;
    __syncthreads();                                   // table visible

    // ---- stage slab 0 into buf 0 ----
#pragma unroll
    for (int l = 0; l < 2; ++l) {
        if (sval[l]) {
            uint4 g = *(const uint4*)(tableL + xv[l] * 8);
            *(uint4*)((unsigned short*)As + loff[l]) = g;
        }
    }
#pragma unroll
    for (int l = 0; l < 2; ++l) xv[l] = sval[l] ? xptr[l][SLABP] : VOCABP;
    LDS_BARRIER();

    // ---- B prefetch prologue: g=0,1 ----
    bf16x8 bc0[2], bc1[2], bc2[2] = {};
    bc0[0] = *(const bf16x8*)(Wtf + boff0);
    bc0[1] = *(const bf16x8*)(Wtf + boff1);
    bc1[0] = *(const bf16x8*)(Wtf + PLANE + boff0);
    bc1[1] = *(const bf16x8*)(Wtf + PLANE + boff1);

    int buf = 0;
    for (int s = 0; s < NSLAB; ++s) {
        // issue x loads for slab s+2 early (vmcnt; a full slab of cover)
        if (s + 2 < NSLAB) {
#pragma unroll
            for (int l = 0; l < 2; ++l)
                xn[l] = sval[l] ? xptr[l][(s + 2) * SLABP] : VOCABP;
        }

        // ---- 5 BK=32 iterations from As[buf]; B depth-2 register pipeline ----
        const unsigned short* Asb = (const unsigned short*)As + buf * (MAXROWS * AROWSH);
#pragma unroll
        for (int kt = 0; kt < 5; ++kt) {
            const int g = s * 5 + kt;
            if (g + 2 < NG) {
                const unsigned short* Wp = Wtf + (size_t)(g + 2) * PLANE;
                bc2[0] = *(const bf16x8*)(Wp + boff0);
                bc2[1] = *(const bf16x8*)(Wp + boff1);
            }
            bf16x8 af[MAXT];
#pragma unroll
            for (int i = 0; i < MAXT; ++i)
                if (i < nt)
                    af[i] = *(const bf16x8*)(Asb + (i * 16 + r16) * AROWSH + (kt * 4 + q) * 8);
#pragma unroll
            for (int i = 0; i < MAXT; ++i)
                if (i < nt) {
                    acc[i][0] = __builtin_amdgcn_mfma_f32_16x16x32_bf16(af[i], bc0[0], acc[i][0], 0, 0, 0);
                    acc[i][1] = __builtin_amdgcn_mfma_f32_16x16x32_bf16(af[i], bc0[1], acc[i][1], 0, 0, 0);
                }
            bc0[0] = bc1[0]; bc0[1] = bc1[1];
            bc1[0] = bc2[0]; bc1[1] = bc2[1];
        }

        // ---- stage slab s+1 into buf^1 (drains into the barrier) ----
        if (s + 1 < NSLAB) {
            unsigned short* d = (unsigned short*)As + (buf ^ 1) * (MAXROWS * AROWSH);
#pragma unroll
            for (int l = 0; l < 2; ++l) {
                if (sval[l]) {
                    uint4 g = *(const uint4*)(tableL + xv[l] * 8);
                    *(uint4*)(d + loff[l]) = g;
                }
            }
        }
#pragma unroll
        for (int l = 0; l < 2; ++l) xv[l] = xn[l];
        LDS_BARRIER();
        buf ^= 1;
    }

    // ---- epilogue: gate + per-batch max in registers, atomicMax flush ----
    // C/D layout: col = lane&15 (n), row = q*4 + reg (m).
    const float b1v = b1[o], b2v = b2[o];
    float cur = 0.0f;
    int curb  = (m0 + q * 4) / TWIN;
#pragma unroll
    for (int i = 0; i < MAXT; ++i) {
        if (i < nt) {
#pragma unroll
            for (int rg = 0; rg < 4; ++rg) {
                const int row = m0 + i * 16 + q * 4 + rg;
                if (row < MROWS) {
                    const int bb = row / TWIN;
                    if (bb != curb) {
                        atomicMax((int*)&pool[curb * COUT + o], __float_as_int(cur));
                        cur = 0.0f; curb = bb;
                    }
                    const float c1 = acc[i][0][rg] + b1v;
                    const float c2 = acc[i][1][rg] + b2v;
                    const float g  = fmaxf(c1, 0.0f) / (1.0f + __expf(-c2));
                    cur = fmaxf(cur, g);
                }
            }
        }
    }
    atomicMax((int*)&pool[curb * COUT + o], __float_as_int(cur));
}

// ---------------- kernel 3: dense head ----------------
__global__ __launch_bounds__(128) void head_kernel(const float* __restrict__ pool,
                                                   const float* __restrict__ wd1,
                                                   const float* __restrict__ bd1,
                                                   const float* __restrict__ wd2,
                                                   const float* __restrict__ bd2,
                                                   float* __restrict__ out) {
    __shared__ float red[BATCH][COUT];
    int j = threadIdx.x;                               // 0..127
    float wj = wd2[j];
#pragma unroll
    for (int b = 0; b < BATCH; ++b) {
        float s = bd1[j];
        for (int i = 0; i < COUT; ++i) s += pool[b * COUT + i] * wd1[j * COUT + i];
        red[b][j] = fmaxf(s, 0.0f) * wj;
    }
    __syncthreads();
    if (j < BATCH) {
        float s = 0.0f;
        for (int i = 0; i < COUT; ++i) s += red[j][i];
        out[j] = 1.0f / (1.0f + expf(-(s + bd2[0])));
    }
}

// ---------------- launch ----------------
extern "C" void kernel_launch(void* const* d_in, const int* in_sizes, int n_in,
                              void* d_out, int out_size, void* d_ws, size_t ws_size,
                              hipStream_t stream) {
    const int*   x   = (const int*)d_in[0];
    const float* emb = (const float*)d_in[1];
    const float* w1  = (const float*)d_in[2];
    const float* b1  = (const float*)d_in[3];
    const float* w2  = (const float*)d_in[4];
    const float* b2  = (const float*)d_in[5];
    const float* wd1 = (const float*)d_in[6];
    const float* bd1 = (const float*)d_in[7];
    const float* wd2 = (const float*)d_in[8];
    const float* bd2 = (const float*)d_in[9];
    float* out = (float*)d_out;

    unsigned short* Wtf  = (unsigned short*)((char*)d_ws + WTF_OFF);
    float*          pool = (float*)((char*)d_ws + POOL_OFF);

    wprep_kernel<<<dim3(NDIM), dim3(256), 0, stream>>>(w1, w2, Wtf, pool);
    gemm_kernel<<<dim3(GRID), dim3(512), 0, stream>>>(x, emb, Wtf, b1, b2, pool);
    head_kernel<<<dim3(1), dim3(128), 0, stream>>>(pool, wd1, bd1, wd2, bd2, out);
}

// Round 12
// 181.428 us; speedup vs baseline: 1.0871x; 1.0871x over previous
//
#include <hip/hip_runtime.h>

// ---------------- problem constants ----------------
#define BATCH   8
#define LSEQ    1048576          // 1<<20
#define KCONV   500
#define TWIN    2097             // (L-K)/K + 1
#define MROWS   16776            // BATCH*TWIN
#define KDIM    4000             // KCONV * C_IN
#define NDIM    256              // 2 * C_OUT
#define COUT    128
#define VOCAB   257
#define VOCABP  256              // padding row of emb (zeros)

#define BMR     80               // m-rows per block (5 x 16)
#define NTILE   210              // ceil(MROWS/80): fits 256 CUs, no serial tail
#define SLABP   20               // positions per slab = 160 k = 5 BK32 iters
#define NSLAB   25
#define NG      125              // total BK32 iterations
#define PLANE   (NDIM * 32)      // 8192 shorts per g-plane of Wtf
#define AROWSH  168              // padded shorts per A-slab row (160 + 8)
#define STAGEN  (BMR * SLABP)    // 1600 gathers per slab

// ---------------- ws layout (bytes) ----------------
#define WTF_OFF   0ull
#define WTF_BYTES ((size_t)NG * PLANE * 2)                  // 2,048,000
#define POOL_OFF  (WTF_OFF + WTF_BYTES)                     // 1024 floats

typedef __attribute__((ext_vector_type(8))) __bf16 bf16x8;
typedef __attribute__((ext_vector_type(4))) float  floatx4;

__device__ inline unsigned short f2bf(float f) {
    union { float f; unsigned u; } c; c.f = f;
    return (unsigned short)((c.u + 0x7FFFu + ((c.u >> 16) & 1u)) >> 16);
}
__device__ inline unsigned pack2(float lo, float hi) {
    return (unsigned)f2bf(lo) | ((unsigned)f2bf(hi) << 16);
}

// barrier that waits ONLY for LDS ops — leaves global (B/x prefetch) loads in flight
#define LDS_BARRIER() asm volatile("s_waitcnt lgkmcnt(0)\n\ts_barrier" ::: "memory")

// ---------------- kernel 1: frag-major weights + zero pool ----------------
// Wtf[g][n][kk] = w_n[e=(g*32+kk)&7][p=(g*32+kk)>>3]
__global__ __launch_bounds__(256) void wprep_kernel(const float* __restrict__ w1,
                                                    const float* __restrict__ w2,
                                                    unsigned short* __restrict__ Wtf,
                                                    float* __restrict__ pool) {
    const int n   = blockIdx.x;                        // 0..255
    const int tid = threadIdx.x;
    __shared__ float tile[KDIM];                       // 16 KB
    const float* src = (n < COUT) ? (w1 + (size_t)n * KDIM)
                                  : (w2 + (size_t)(n - COUT) * KDIM);
    for (int i = tid; i < KDIM; i += 256) tile[i] = src[i];
    __syncthreads();
    for (int i = tid; i < KDIM; i += 256) {
        int g = i >> 5, kk = i & 31;
        Wtf[(size_t)g * PLANE + n * 32 + kk] = f2bf(tile[(i & 7) * KCONV + (i >> 3)]);
    }
    if (n == 0 && tid < BATCH * COUT / 2)
        ((float2*)pool)[tid] = float2{0.f, 0.f};
}

// ---------------- kernel 2: fused embed + full-K GEMM + gate + max-pool ----------------
// Grid 210 x 512 thr (8 waves), Wm=2 x Wn=4 wave split:
//   wg = wv>>2: m-tile group (group 0: tiles 0-2, group 1: tiles 3-4)
//   wn = wv&3 : o-quarter; lane (r16,q) handles o in {wn*32+r16, +16} for c1 and +128 for c2
// Per-CU per-kt: af LDS reads 20 b128 (was 40 at Wm=1), B 32 KB from L2 (VMEM pipe,
// depth-2 prefetch), MFMA per SIMD = 12+8 = 20 (balanced pairs). Staging, ordering,
// LDS_BARRIER, epilogue scheme identical to r10.
__global__ __launch_bounds__(512) void gemm_kernel(const int* __restrict__ x,
                                                   const float* __restrict__ emb,
                                                   const unsigned short* __restrict__ Wtf,
                                                   const float* __restrict__ b1,
                                                   const float* __restrict__ b2,
                                                   float* __restrict__ pool) {
    __shared__ unsigned short tableL[VOCAB * 8];       // 4112 B
    __shared__ unsigned short As[2][BMR * AROWSH];     // 2 x 26.25 KB

    const int tid  = threadIdx.x;
    const int lane = tid & 63;
    const int wv   = tid >> 6;                         // 0..7
    const int m0   = blockIdx.x * BMR;
    const int r16  = lane & 15;
    const int q    = lane >> 4;                        // 0..3

    const int wg   = wv >> 2;                          // 0: tiles 0-2, 1: tiles 3-4
    const int wn   = wv & 3;                           // o-quarter
    const int ntw  = wg ? 2 : 3;                       // tiles for this wave
    const int tb   = wg * 3;                           // first tile index

    // ---- build bf16 emb table in LDS ----
    if (tid < VOCAB) {
        const float4* er = (const float4*)(emb + tid * 8);
        float4 a = er[0], b = er[1];
        uint4 u;
        u.x = pack2(a.x, a.y); u.y = pack2(a.z, a.w);
        u.z = pack2(b.x, b.y); u.w = pack2(b.z, b.w);
        *(uint4*)(tableL + tid * 8) = u;
    }

    // ---- staging roles: thread handles idx = tid + 512*l (idx < 1600) ----
    const int* xptr[4];
    int        loff[4];
    bool       sval[4];
#pragma unroll
    for (int l = 0; l < 4; ++l) {
        int idx = tid + 512 * l;
        sval[l] = (idx < STAGEN);
        int ic  = sval[l] ? idx : 0;
        int row = ic / SLABP;
        int pos = ic - row * SLABP;
        int am  = m0 + row;
        bool av = sval[l] && (am < MROWS);
        sval[l] = av;
        int amc = av ? am : 0;
        int b   = amc / TWIN;
        int t   = amc - b * TWIN;
        xptr[l] = x + ((size_t)b * LSEQ + (size_t)t * KCONV + pos);
        loff[l] = row * AROWSH + pos * 8;
    }

    // ---- compute role: 4 B-frag offsets (shorts) ----
    // j: 0 -> n = wn*32 + r16 (c1 lo), 1 -> +16 (c1 hi), 2 -> +128 (c2 lo), 3 -> +144 (c2 hi)
    const size_t bb0 = (size_t)(wn * 32 + r16) * 32 + q * 8;
    const size_t boff[4] = { bb0, bb0 + 16 * 32, bb0 + 128 * 32, bb0 + 144 * 32 };

    floatx4 acc[3][4];
#pragma unroll
    for (int i = 0; i < 3; ++i)
#pragma unroll
        for (int j = 0; j < 4; ++j) acc[i][j] = floatx4{0.f, 0.f, 0.f, 0.f};

    // ---- x values for slab 0 ----
    int xv[4], xn[4];
#pragma unroll
    for (int l = 0; l < 4; ++l) xv[l] = sval[l] ? xptr[l][0] : VOCABP;
    __syncthreads();                                   // table visible

    // ---- stage slab 0 into buf 0 ----
#pragma unroll
    for (int l = 0; l < 4; ++l) {
        if (l == 3 && tid >= STAGEN - 3 * 512) break;
        uint4 g = *(const uint4*)(tableL + xv[l] * 8);
        *(uint4*)((unsigned short*)As + loff[l]) = g;
    }
#pragma unroll
    for (int l = 0; l < 4; ++l) xv[l] = sval[l] ? xptr[l][SLABP] : VOCABP;
    LDS_BARRIER();

    // ---- B prefetch prologue: g=0,1 ----
    bf16x8 bc0[4], bc1[4], bc2[4] = {};
#pragma unroll
    for (int j = 0; j < 4; ++j) {
        bc0[j] = *(const bf16x8*)(Wtf + boff[j]);
        bc1[j] = *(const bf16x8*)(Wtf + PLANE + boff[j]);
    }

    int buf = 0;
    for (int s = 0; s < NSLAB; ++s) {
        // issue x loads for slab s+2 early (vmcnt; a full slab of cover)
        if (s + 2 < NSLAB) {
#pragma unroll
            for (int l = 0; l < 4; ++l)
                xn[l] = sval[l] ? xptr[l][(s + 2) * SLABP] : VOCABP;
        }

        // ---- 5 BK=32 iterations from As[buf]; B depth-2 register pipeline ----
        const unsigned short* Asb = (const unsigned short*)As + buf * (BMR * AROWSH);
#pragma unroll
        for (int kt = 0; kt < 5; ++kt) {
            const int g = s * 5 + kt;
            if (g + 2 < NG) {
                const unsigned short* Wp = Wtf + (size_t)(g + 2) * PLANE;
#pragma unroll
                for (int j = 0; j < 4; ++j) bc2[j] = *(const bf16x8*)(Wp + boff[j]);
            }
            bf16x8 af[3];
#pragma unroll
            for (int i = 0; i < 3; ++i)
                if (i < ntw)
                    af[i] = *(const bf16x8*)(Asb + ((tb + i) * 16 + r16) * AROWSH + (kt * 4 + q) * 8);
#pragma unroll
            for (int i = 0; i < 3; ++i)
                if (i < ntw) {
#pragma unroll
                    for (int j = 0; j < 4; ++j)
                        acc[i][j] = __builtin_amdgcn_mfma_f32_16x16x32_bf16(af[i], bc0[j], acc[i][j], 0, 0, 0);
                }
#pragma unroll
            for (int j = 0; j < 4; ++j) { bc0[j] = bc1[j]; bc1[j] = bc2[j]; }
        }

        // ---- stage slab s+1 into buf^1 (drains into the barrier) ----
        if (s + 1 < NSLAB) {
            unsigned short* d = (unsigned short*)As + (buf ^ 1) * (BMR * AROWSH);
#pragma unroll
            for (int l = 0; l < 4; ++l) {
                if (l == 3 && tid >= STAGEN - 3 * 512) break;
                uint4 g = *(const uint4*)(tableL + xv[l] * 8);
                *(uint4*)(d + loff[l]) = g;
            }
        }
#pragma unroll
        for (int l = 0; l < 4; ++l) xv[l] = xn[l];
        LDS_BARRIER();
        buf ^= 1;
    }

    // ---- epilogue: gate + per-batch max in registers, atomicMax flush ----
    // C/D layout: col = lane&15 (n), row = q*4 + reg (m). Lane holds 2 o-values.
#pragma unroll
    for (int jj = 0; jj < 2; ++jj) {
        const int o = wn * 32 + jj * 16 + r16;         // 0..127
        const float b1v = b1[o], b2v = b2[o];
        float cur = 0.0f;
        int curb  = (m0 + tb * 16 + q * 4) / TWIN;
#pragma unroll
        for (int i = 0; i < 3; ++i) {
            if (i < ntw) {
#pragma unroll
                for (int rg = 0; rg < 4; ++rg) {
                    const int row = m0 + (tb + i) * 16 + q * 4 + rg;
                    if (row < MROWS) {
                        const int bb = row / TWIN;
                        if (bb != curb) {
                            atomicMax((int*)&pool[curb * COUT + o], __float_as_int(cur));
                            cur = 0.0f; curb = bb;
                        }
                        const float c1 = acc[i][jj][rg] + b1v;
                        const float c2 = acc[i][jj + 2][rg] + b2v;
                        const float g  = fmaxf(c1, 0.0f) / (1.0f + __expf(-c2));
                        cur = fmaxf(cur, g);
                    }
                }
            }
        }
        atomicMax((int*)&pool[curb * COUT + o], __float_as_int(cur));
    }
}

// ---------------- kernel 3: dense head ----------------
__global__ __launch_bounds__(128) void head_kernel(const float* __restrict__ pool,
                                                   const float* __restrict__ wd1,
                                                   const float* __restrict__ bd1,
                                                   const float* __restrict__ wd2,
                                                   const float* __restrict__ bd2,
                                                   float* __restrict__ out) {
    __shared__ float red[BATCH][COUT];
    int j = threadIdx.x;                               // 0..127
    float wj = wd2[j];
#pragma unroll
    for (int b = 0; b < BATCH; ++b) {
        float s = bd1[j];
        for (int i = 0; i < COUT; ++i) s += pool[b * COUT + i] * wd1[j * COUT + i];
        red[b][j] = fmaxf(s, 0.0f) * wj;
    }
    __syncthreads();
    if (j < BATCH) {
        float s = 0.0f;
        for (int i = 0; i < COUT; ++i) s += red[j][i];
        out[j] = 1.0f / (1.0f + expf(-(s + bd2[0])));
    }
}

// ---------------- launch ----------------
extern "C" void kernel_launch(void* const* d_in, const int* in_sizes, int n_in,
                              void* d_out, int out_size, void* d_ws, size_t ws_size,
                              hipStream_t stream) {
    const int*   x   = (const int*)d_in[0];
    const float* emb = (const float*)d_in[1];
    const float* w1  = (const float*)d_in[2];
    const float* b1  = (const float*)d_in[3];
    const float* w2  = (const float*)d_in[4];
    const float* b2  = (const float*)d_in[5];
    const float* wd1 = (const float*)d_in[6];
    const float* bd1 = (const float*)d_in[7];
    const float* wd2 = (const float*)d_in[8];
    const float* bd2 = (const float*)d_in[9];
    float* out = (float*)d_out;

    unsigned short* Wtf  = (unsigned short*)((char*)d_ws + WTF_OFF);
    float*          pool = (float*)((char*)d_ws + POOL_OFF);

    wprep_kernel<<<dim3(NDIM), dim3(256), 0, stream>>>(w1, w2, Wtf, pool);
    gemm_kernel<<<dim3(NTILE), dim3(512), 0, stream>>>(x, emb, Wtf, b1, b2, pool);
    head_kernel<<<dim3(1), dim3(128), 0, stream>>>(pool, wd1, bd1, wd2, bd2, out);
}

// Round 13
// 180.817 us; speedup vs baseline: 1.0907x; 1.0034x over previous
//
#include <hip/hip_runtime.h>

// ---------------- problem constants ----------------
#define BATCH   8
#define LSEQ    1048576          // 1<<20
#define KCONV   500
#define TWIN    2097             // (L-K)/K + 1
#define MROWS   16776            // BATCH*TWIN
#define KDIM    4000             // KCONV * C_IN
#define NDIM    256              // 2 * C_OUT
#define COUT    128
#define VOCAB   257
#define VOCABP  256              // padding row of emb (zeros)

#define BMR     80               // m-rows per block (5 x 16)
#define NTILE   210              // ceil(MROWS/80): fits 256 CUs, no serial tail
#define SLABP   20               // positions per slab = 160 k = 5 BK32 iters
#define NSLAB   25
#define NG      125              // total BK32 iterations
#define PLANE   (NDIM * 32)      // 8192 shorts per g-plane of Wtf
#define AROWSH  168              // padded shorts per A-slab row (336 B, 16B-aligned)
#define STAGEN  (BMR * SLABP)    // 1600 stage items per slab
#define NSL     7                // staging slots per stager thread (256 stagers)

// ---------------- ws layout (bytes) ----------------
#define WTF_OFF   0ull
#define WTF_BYTES ((size_t)NG * PLANE * 2)                  // 2,048,000
#define POOL_OFF  (WTF_OFF + WTF_BYTES)                     // 1024 floats

typedef __attribute__((ext_vector_type(8))) __bf16 bf16x8;
typedef __attribute__((ext_vector_type(4))) float  floatx4;

__device__ inline unsigned short f2bf(float f) {
    union { float f; unsigned u; } c; c.f = f;
    return (unsigned short)((c.u + 0x7FFFu + ((c.u >> 16) & 1u)) >> 16);
}
__device__ inline unsigned pack2(float lo, float hi) {
    return (unsigned)f2bf(lo) | ((unsigned)f2bf(hi) << 16);
}

// barrier that waits ONLY for LDS ops — leaves global (B/x prefetch) loads in flight
#define LDS_BARRIER() asm volatile("s_waitcnt lgkmcnt(0)\n\ts_barrier" ::: "memory")

// ---------------- kernel 1: frag-major weights + zero pool ----------------
// Wtf[g][n][kk] = w_n[e=(g*32+kk)&7][p=(g*32+kk)>>3]
__global__ __launch_bounds__(256) void wprep_kernel(const float* __restrict__ w1,
                                                    const float* __restrict__ w2,
                                                    unsigned short* __restrict__ Wtf,
                                                    float* __restrict__ pool) {
    const int n   = blockIdx.x;                        // 0..255
    const int tid = threadIdx.x;
    __shared__ float tile[KDIM];                       // 16 KB
    const float* src = (n < COUT) ? (w1 + (size_t)n * KDIM)
                                  : (w2 + (size_t)(n - COUT) * KDIM);
    for (int i = tid; i < KDIM; i += 256) tile[i] = src[i];
    __syncthreads();
    for (int i = tid; i < KDIM; i += 256) {
        int g = i >> 5, kk = i & 31;
        Wtf[(size_t)g * PLANE + n * 32 + kk] = f2bf(tile[(i & 7) * KCONV + (i >> 3)]);
    }
    if (n == 0 && tid < BATCH * COUT / 2)
        ((float2*)pool)[tid] = float2{0.f, 0.f};
}

// ---------------- kernel 2: producer-consumer fused embed+GEMM+gate+max-pool ----------------
// Grid 210 x 512 thr. Waves 0-3 = COMPUTE: wave wv owns o-quarter wv*32..+31;
//   lane (r16,q): acc[i][j], j=0/1 -> c1 at o, o+16; j=2/3 -> c2 (n+128). 20 MFMA/kt.
//   Its lgkm queue holds ONLY its 5 af ds_reads per kt -> fine-grained waits.
// Waves 4-7 = STAGERS: x loads (one slab ahead, vmcnt-covered) + tableL gathers ->
//   As[buf^1] writes, meeting compute at the lgkm-only LDS_BARRIER each slab.
// B: frag-major Wtf, coalesced 1KB register loads, depth-2 prefetch (never drained
// by the barrier). Pad rows staged as VOCABP zeros.
__global__ __launch_bounds__(512, 2) void gemm_kernel(const int* __restrict__ x,
                                                      const float* __restrict__ emb,
                                                      const unsigned short* __restrict__ Wtf,
                                                      const float* __restrict__ b1,
                                                      const float* __restrict__ b2,
                                                      float* __restrict__ pool) {
    __shared__ unsigned short tableL[VOCAB * 8];       // 4112 B
    __shared__ unsigned short As[2][BMR * AROWSH];     // 2 x 26.25 KB

    const int tid  = threadIdx.x;
    const int lane = tid & 63;
    const int wv   = tid >> 6;                         // 0..7
    const int m0   = blockIdx.x * BMR;
    const int r16  = lane & 15;
    const int q    = lane >> 4;                        // 0..3
    const bool stager = (wv >= 4);
    const int tid2 = tid & 255;                        // stager index

    // ---- stager role precompute: slot l handles idx = tid2 + 256*l ----
    const int* xptr[NSL];
    int  loff[NSL];
    bool wval[NSL], sval[NSL];
    int  xv[NSL], xn[NSL];
    if (stager) {
#pragma unroll
        for (int l = 0; l < NSL; ++l) {
            int idx = tid2 + 256 * l;
            wval[l] = (idx < STAGEN);
            int ic  = wval[l] ? idx : 0;
            int row = ic / SLABP;
            int pos = ic - row * SLABP;
            int am  = m0 + row;
            sval[l] = wval[l] && (am < MROWS);
            int amc = (am < MROWS) ? am : 0;
            int b   = amc / TWIN;
            int t   = amc - b * TWIN;
            xptr[l] = x + ((size_t)b * LSEQ + (size_t)t * KCONV + pos);
            loff[l] = row * AROWSH + pos * 8;
        }
        // issue slab-0 x loads immediately (latency covered by table build + barrier)
#pragma unroll
        for (int l = 0; l < NSL; ++l) xv[l] = sval[l] ? xptr[l][0] : VOCABP;
    }

    // ---- build bf16 emb table in LDS (all waves, tid < 257) ----
    if (tid < VOCAB) {
        const float4* er = (const float4*)(emb + tid * 8);
        float4 a = er[0], b = er[1];
        uint4 u;
        u.x = pack2(a.x, a.y); u.y = pack2(a.z, a.w);
        u.z = pack2(b.x, b.y); u.w = pack2(b.z, b.w);
        *(uint4*)(tableL + tid * 8) = u;
    }

    // ---- compute role constants ----
    const size_t bb0 = (size_t)(wv * 32 + r16) * 32 + q * 8;   // valid for wv<4
    const size_t boff[4] = { bb0, bb0 + 16 * 32, bb0 + 128 * 32, bb0 + 144 * 32 };
    floatx4 acc[5][4];
#pragma unroll
    for (int i = 0; i < 5; ++i)
#pragma unroll
        for (int j = 0; j < 4; ++j) acc[i][j] = floatx4{0.f, 0.f, 0.f, 0.f};
    bf16x8 bc0[4], bc1[4], bc2[4] = {};

    __syncthreads();                                   // table visible to stagers

    if (stager) {
        // stage slab 0 into buf 0; then x for slab 1
#pragma unroll
        for (int l = 0; l < NSL; ++l) {
            if (wval[l]) {
                uint4 g = *(const uint4*)(tableL + xv[l] * 8);
                *(uint4*)((unsigned short*)As + loff[l]) = g;
            }
        }
#pragma unroll
        for (int l = 0; l < NSL; ++l) xv[l] = sval[l] ? xptr[l][SLABP] : VOCABP;
    } else {
        // B prefetch prologue: g = 0, 1
#pragma unroll
        for (int j = 0; j < 4; ++j) {
            bc0[j] = *(const bf16x8*)(Wtf + boff[j]);
            bc1[j] = *(const bf16x8*)(Wtf + PLANE + boff[j]);
        }
    }
    LDS_BARRIER();

    int buf = 0;
    for (int s = 0; s < NSLAB; ++s) {
        if (stager) {
            // x loads for slab s+2 (vmcnt; a full slab of cover)
            if (s + 2 < NSLAB) {
#pragma unroll
                for (int l = 0; l < NSL; ++l)
                    xn[l] = sval[l] ? xptr[l][(s + 2) * SLABP] : VOCABP;
            }
            // stage slab s+1 into buf^1
            if (s + 1 < NSLAB) {
                unsigned short* d = (unsigned short*)As + (buf ^ 1) * (BMR * AROWSH);
#pragma unroll
                for (int l = 0; l < NSL; ++l) {
                    if (wval[l]) {
                        uint4 g = *(const uint4*)(tableL + xv[l] * 8);
                        *(uint4*)(d + loff[l]) = g;
                    }
                }
            }
#pragma unroll
            for (int l = 0; l < NSL; ++l) xv[l] = xn[l];
        } else {
            // 5 BK=32 iterations from As[buf]; B depth-2 register pipeline
            const unsigned short* Asb = (const unsigned short*)As + buf * (BMR * AROWSH);
#pragma unroll
            for (int kt = 0; kt < 5; ++kt) {
                const int g = s * 5 + kt;
                if (g + 2 < NG) {
                    const unsigned short* Wp = Wtf + (size_t)(g + 2) * PLANE;
#pragma unroll
                    for (int j = 0; j < 4; ++j) bc2[j] = *(const bf16x8*)(Wp + boff[j]);
                }
                bf16x8 af[5];
#pragma unroll
                for (int i = 0; i < 5; ++i)
                    af[i] = *(const bf16x8*)(Asb + (i * 16 + r16) * AROWSH + (kt * 4 + q) * 8);
#pragma unroll
                for (int i = 0; i < 5; ++i)
#pragma unroll
                    for (int j = 0; j < 4; ++j)
                        acc[i][j] = __builtin_amdgcn_mfma_f32_16x16x32_bf16(af[i], bc0[j], acc[i][j], 0, 0, 0);
#pragma unroll
                for (int j = 0; j < 4; ++j) { bc0[j] = bc1[j]; bc1[j] = bc2[j]; }
            }
        }
        LDS_BARRIER();
        buf ^= 1;
    }

    // ---- epilogue (compute waves only): gate + per-batch max, atomicMax flush ----
    // C/D layout: col = lane&15 (n), row = q*4 + reg (m). Lane holds 2 o-values.
    if (!stager) {
#pragma unroll
        for (int jj = 0; jj < 2; ++jj) {
            const int o = wv * 32 + jj * 16 + r16;     // 0..127
            const float b1v = b1[o], b2v = b2[o];
            float cur = 0.0f;
            int curb  = (m0 + q * 4) / TWIN;
#pragma unroll
            for (int i = 0; i < 5; ++i) {
#pragma unroll
                for (int rg = 0; rg < 4; ++rg) {
                    const int row = m0 + i * 16 + q * 4 + rg;
                    if (row < MROWS) {
                        const int bb = row / TWIN;
                        if (bb != curb) {
                            atomicMax((int*)&pool[curb * COUT + o], __float_as_int(cur));
                            cur = 0.0f; curb = bb;
                        }
                        const float c1 = acc[i][jj][rg] + b1v;
                        const float c2 = acc[i][jj + 2][rg] + b2v;
                        const float g  = fmaxf(c1, 0.0f) / (1.0f + __expf(-c2));
                        cur = fmaxf(cur, g);
                    }
                }
            }
            atomicMax((int*)&pool[curb * COUT + o], __float_as_int(cur));
        }
    }
}

// ---------------- kernel 3: dense head ----------------
__global__ __launch_bounds__(128) void head_kernel(const float* __restrict__ pool,
                                                   const float* __restrict__ wd1,
                                                   const float* __restrict__ bd1,
                                                   const float* __restrict__ wd2,
                                                   const float* __restrict__ bd2,
                                                   float* __restrict__ out) {
    __shared__ float red[BATCH][COUT];
    int j = threadIdx.x;                               // 0..127
    float wj = wd2[j];
#pragma unroll
    for (int b = 0; b < BATCH; ++b) {
        float s = bd1[j];
        for (int i = 0; i < COUT; ++i) s += pool[b * COUT + i] * wd1[j * COUT + i];
        red[b][j] = fmaxf(s, 0.0f) * wj;
    }
    __syncthreads();
    if (j < BATCH) {
        float s = 0.0f;
        for (int i = 0; i < COUT; ++i) s += red[j][i];
        out[j] = 1.0f / (1.0f + expf(-(s + bd2[0])));
    }
}

// ---------------- launch ----------------
extern "C" void kernel_launch(void* const* d_in, const int* in_sizes, int n_in,
                              void* d_out, int out_size, void* d_ws, size_t ws_size,
                              hipStream_t stream) {
    const int*   x   = (const int*)d_in[0];
    const float* emb = (const float*)d_in[1];
    const float* w1  = (const float*)d_in[2];
    const float* b1  = (const float*)d_in[3];
    const float* w2  = (const float*)d_in[4];
    const float* b2  = (const float*)d_in[5];
    const float* wd1 = (const float*)d_in[6];
    const float* bd1 = (const float*)d_in[7];
    const float* wd2 = (const float*)d_in[8];
    const float* bd2 = (const float*)d_in[9];
    float* out = (float*)d_out;

    unsigned short* Wtf  = (unsigned short*)((char*)d_ws + WTF_OFF);
    float*          pool = (float*)((char*)d_ws + POOL_OFF);

    wprep_kernel<<<dim3(NDIM), dim3(256), 0, stream>>>(w1, w2, Wtf, pool);
    gemm_kernel<<<dim3(NTILE), dim3(512), 0, stream>>>(x, emb, Wtf, b1, b2, pool);
    head_kernel<<<dim3(1), dim3(128), 0, stream>>>(pool, wd1, bd1, wd2, bd2, out);
}

// Round 14
// 176.620 us; speedup vs baseline: 1.1167x; 1.0238x over previous
//
#include <hip/hip_runtime.h>

// ---------------- problem constants ----------------
#define BATCH   8
#define LSEQ    1048576          // 1<<20
#define KCONV   500
#define TWIN    2097             // (L-K)/K + 1
#define MROWS   16776            // BATCH*TWIN
#define KDIM    4000             // KCONV * C_IN
#define NDIM    256              // 2 * C_OUT
#define COUT    128
#define VOCAB   257
#define VOCABP  256              // padding row of emb (zeros)

#define BMR     80               // m-rows per block (5 x 16)
#define NTILE   210              // ceil(MROWS/80): fits 256 CUs, no serial tail
#define SLABP   20               // positions per slab = 160 k = 5 BK32 iters
#define NSLAB   25
#define NG      125              // total BK32 iterations
#define PLANE   (NDIM * 32)      // 8192 shorts per g-plane of Wtf
#define AROWSH  168              // padded shorts per A-slab row (160 + 8)
#define STAGEN  (BMR * SLABP)    // 1600 gathers per slab

// ---------------- ws layout (bytes) ----------------
#define WTF_OFF   0ull
#define WTF_BYTES ((size_t)NG * PLANE * 2)                  // 2,048,000
#define POOL_OFF  (WTF_OFF + WTF_BYTES)                     // 1024 floats

typedef __attribute__((ext_vector_type(8))) __bf16 bf16x8;
typedef __attribute__((ext_vector_type(4))) float  floatx4;

__device__ inline unsigned short f2bf(float f) {
    union { float f; unsigned u; } c; c.f = f;
    return (unsigned short)((c.u + 0x7FFFu + ((c.u >> 16) & 1u)) >> 16);
}
__device__ inline unsigned pack2(float lo, float hi) {
    return (unsigned)f2bf(lo) | ((unsigned)f2bf(hi) << 16);
}

// barrier that waits ONLY for LDS ops — leaves global (B/x prefetch) loads in flight
#define LDS_BARRIER() asm volatile("s_waitcnt lgkmcnt(0)\n\ts_barrier" ::: "memory")

// ---------------- kernel 1: frag-major weights + zero pool ----------------
// Wtf[g][n][kk] = w_n[e=(g*32+kk)&7][p=(g*32+kk)>>3]
__global__ __launch_bounds__(256) void wprep_kernel(const float* __restrict__ w1,
                                                    const float* __restrict__ w2,
                                                    unsigned short* __restrict__ Wtf,
                                                    float* __restrict__ pool) {
    const int n   = blockIdx.x;                        // 0..255
    const int tid = threadIdx.x;
    __shared__ float tile[KDIM];                       // 16 KB
    const float* src = (n < COUT) ? (w1 + (size_t)n * KDIM)
                                  : (w2 + (size_t)(n - COUT) * KDIM);
    for (int i = tid; i < KDIM; i += 256) tile[i] = src[i];
    __syncthreads();
    for (int i = tid; i < KDIM; i += 256) {
        int g = i >> 5, kk = i & 31;
        Wtf[(size_t)g * PLANE + n * 32 + kk] = f2bf(tile[(i & 7) * KCONV + (i >> 3)]);
    }
    if (n == 0 && tid < BATCH * COUT / 2)
        ((float2*)pool)[tid] = float2{0.f, 0.f};
}

// ---------------- kernel 2: fused embed + full-K GEMM + gate + max-pool ----------------
// Grid 210 x 512 thr (8 waves). Wave wv, lane (r16,q): o = wv*16 + r16 (0..127);
// acc[i][0]=c1, acc[i][1]=c2 (n=o+128) -> gate fully in registers.
// A: LDS emb table (gathers via the 32-bank crossbar, not the L1/TA path — the
//    r3..r7 serializer). Slab double-buffered; compute-then-stage ordering.
// B: frag-major Wtf, coalesced 1KB register loads, depth-2 prefetch; LDS_BARRIER
//    (lgkm-only) never drains them. x prefetched a full slab ahead on vmcnt.
// [r14 note: best measured config — r11/r12/r13 structural variants all regressed;
//  the ~1400 cyc/kt wall is invariant to TLP, pipe load, and wave roles.]
__global__ __launch_bounds__(512) void gemm_kernel(const int* __restrict__ x,
                                                   const float* __restrict__ emb,
                                                   const unsigned short* __restrict__ Wtf,
                                                   const float* __restrict__ b1,
                                                   const float* __restrict__ b2,
                                                   float* __restrict__ pool) {
    __shared__ unsigned short tableL[VOCAB * 8];       // 4112 B
    __shared__ unsigned short As[2][BMR * AROWSH];     // 2 x 26.25 KB

    const int tid  = threadIdx.x;
    const int lane = tid & 63;
    const int wv   = tid >> 6;                         // 0..7
    const int m0   = blockIdx.x * BMR;
    const int r16  = lane & 15;
    const int q    = lane >> 4;                        // 0..3

    // ---- build bf16 emb table in LDS ----
    if (tid < VOCAB) {
        const float4* er = (const float4*)(emb + tid * 8);
        float4 a = er[0], b = er[1];
        uint4 u;
        u.x = pack2(a.x, a.y); u.y = pack2(a.z, a.w);
        u.z = pack2(b.x, b.y); u.w = pack2(b.z, b.w);
        *(uint4*)(tableL + tid * 8) = u;
    }

    // ---- staging roles: thread handles idx = tid + 512*l (idx < 1600) ----
    const int* xptr[4];
    int        loff[4];
    bool       sval[4];
#pragma unroll
    for (int l = 0; l < 4; ++l) {
        int idx = tid + 512 * l;
        sval[l] = (idx < STAGEN);
        int ic  = sval[l] ? idx : 0;
        int row = ic / SLABP;
        int pos = ic - row * SLABP;
        int am  = m0 + row;
        bool av = sval[l] && (am < MROWS);
        sval[l] = av;
        int amc = av ? am : 0;
        int b   = amc / TWIN;
        int t   = amc - b * TWIN;
        xptr[l] = x + ((size_t)b * LSEQ + (size_t)t * KCONV + pos);
        loff[l] = row * AROWSH + pos * 8;
    }

    // ---- compute role ----
    const int o = wv * 16 + r16;                       // 0..127
    const size_t boff0 = (size_t)o * 32 + q * 8;
    const size_t boff1 = (size_t)(o + 128) * 32 + q * 8;

    floatx4 acc[5][2];
#pragma unroll
    for (int i = 0; i < 5; ++i) { acc[i][0] = floatx4{0,0,0,0}; acc[i][1] = floatx4{0,0,0,0}; }

    // ---- x values for slab 0 ----
    int xv[4], xn[4];
#pragma unroll
    for (int l = 0; l < 4; ++l) xv[l] = sval[l] ? xptr[l][0] : VOCABP;
    __syncthreads();                                   // table visible

    // ---- stage slab 0 into buf 0 ----
#pragma unroll
    for (int l = 0; l < 4; ++l) {
        if (l == 3 && tid >= STAGEN - 3 * 512) break;
        uint4 g = *(const uint4*)(tableL + xv[l] * 8);
        *(uint4*)((unsigned short*)As + loff[l]) = g;
    }
#pragma unroll
    for (int l = 0; l < 4; ++l) xv[l] = sval[l] ? xptr[l][SLABP] : VOCABP;
    LDS_BARRIER();

    // ---- B prefetch prologue: g=0,1 ----
    bf16x8 bc0[2], bc1[2], bc2[2] = {};
    bc0[0] = *(const bf16x8*)(Wtf + boff0);
    bc0[1] = *(const bf16x8*)(Wtf + boff1);
    bc1[0] = *(const bf16x8*)(Wtf + PLANE + boff0);
    bc1[1] = *(const bf16x8*)(Wtf + PLANE + boff1);

    int buf = 0;
    for (int s = 0; s < NSLAB; ++s) {
        // issue x loads for slab s+2 early (vmcnt; a full slab of cover)
        if (s + 2 < NSLAB) {
#pragma unroll
            for (int l = 0; l < 4; ++l)
                xn[l] = sval[l] ? xptr[l][(s + 2) * SLABP] : VOCABP;
        }

        // ---- 5 BK=32 iterations from As[buf]; B depth-2 register pipeline ----
        const unsigned short* Asb = (const unsigned short*)As + buf * (BMR * AROWSH);
#pragma unroll
        for (int kt = 0; kt < 5; ++kt) {
            const int g = s * 5 + kt;
            if (g + 2 < NG) {
                const unsigned short* Wp = Wtf + (size_t)(g + 2) * PLANE;
                bc2[0] = *(const bf16x8*)(Wp + boff0);
                bc2[1] = *(const bf16x8*)(Wp + boff1);
            }
            bf16x8 af[5];
#pragma unroll
            for (int i = 0; i < 5; ++i)
                af[i] = *(const bf16x8*)(Asb + (i * 16 + r16) * AROWSH + (kt * 4 + q) * 8);
#pragma unroll
            for (int i = 0; i < 5; ++i) {
                acc[i][0] = __builtin_amdgcn_mfma_f32_16x16x32_bf16(af[i], bc0[0], acc[i][0], 0, 0, 0);
                acc[i][1] = __builtin_amdgcn_mfma_f32_16x16x32_bf16(af[i], bc0[1], acc[i][1], 0, 0, 0);
            }
            bc0[0] = bc1[0]; bc0[1] = bc1[1];
            bc1[0] = bc2[0]; bc1[1] = bc2[1];
        }

        // ---- stage slab s+1 into buf^1 (drains into the barrier) ----
        if (s + 1 < NSLAB) {
            unsigned short* d = (unsigned short*)As + (buf ^ 1) * (BMR * AROWSH);
#pragma unroll
            for (int l = 0; l < 4; ++l) {
                if (l == 3 && tid >= STAGEN - 3 * 512) break;
                uint4 g = *(const uint4*)(tableL + xv[l] * 8);
                *(uint4*)(d + loff[l]) = g;
            }
        }
#pragma unroll
        for (int l = 0; l < 4; ++l) xv[l] = xn[l];
        LDS_BARRIER();
        buf ^= 1;
    }

    // ---- epilogue: gate + per-batch max in registers, atomicMax flush ----
    // C/D layout: col = lane&15 (n), row = q*4 + reg (m).
    const float b1v = b1[o], b2v = b2[o];
    float cur = 0.0f;
    int curb  = (m0 + q * 4) / TWIN;
#pragma unroll
    for (int i = 0; i < 5; ++i) {
#pragma unroll
        for (int rg = 0; rg < 4; ++rg) {
            const int row = m0 + i * 16 + q * 4 + rg;
            if (row < MROWS) {
                const int bb = row / TWIN;
                if (bb != curb) {
                    atomicMax((int*)&pool[curb * COUT + o], __float_as_int(cur));
                    cur = 0.0f; curb = bb;
                }
                const float c1 = acc[i][0][rg] + b1v;
                const float c2 = acc[i][1][rg] + b2v;
                const float g  = fmaxf(c1, 0.0f) / (1.0f + __expf(-c2));
                cur = fmaxf(cur, g);
            }
        }
    }
    atomicMax((int*)&pool[curb * COUT + o], __float_as_int(cur));
}

// ---------------- kernel 3: dense head ----------------
__global__ __launch_bounds__(128) void head_kernel(const float* __restrict__ pool,
                                                   const float* __restrict__ wd1,
                                                   const float* __restrict__ bd1,
                                                   const float* __restrict__ wd2,
                                                   const float* __restrict__ bd2,
                                                   float* __restrict__ out) {
    __shared__ float red[BATCH][COUT];
    int j = threadIdx.x;                               // 0..127
    float wj = wd2[j];
#pragma unroll
    for (int b = 0; b < BATCH; ++b) {
        float s = bd1[j];
        for (int i = 0; i < COUT; ++i) s += pool[b * COUT + i] * wd1[j * COUT + i];
        red[b][j] = fmaxf(s, 0.0f) * wj;
    }
    __syncthreads();
    if (j < BATCH) {
        float s = 0.0f;
        for (int i = 0; i < COUT; ++i) s += red[j][i];
        out[j] = 1.0f / (1.0f + expf(-(s + bd2[0])));
    }
}

// ---------------- launch ----------------
extern "C" void kernel_launch(void* const* d_in, const int* in_sizes, int n_in,
                              void* d_out, int out_size, void* d_ws, size_t ws_size,
                              hipStream_t stream) {
    const int*   x   = (const int*)d_in[0];
    const float* emb = (const float*)d_in[1];
    const float* w1  = (const float*)d_in[2];
    const float* b1  = (const float*)d_in[3];
    const float* w2  = (const float*)d_in[4];
    const float* b2  = (const float*)d_in[5];
    const float* wd1 = (const float*)d_in[6];
    const float* bd1 = (const float*)d_in[7];
    const float* wd2 = (const float*)d_in[8];
    const float* bd2 = (const float*)d_in[9];
    float* out = (float*)d_out;

    unsigned short* Wtf  = (unsigned short*)((char*)d_ws + WTF_OFF);
    float*          pool = (float*)((char*)d_ws + POOL_OFF);

    wprep_kernel<<<dim3(NDIM), dim3(256), 0, stream>>>(w1, w2, Wtf, pool);
    gemm_kernel<<<dim3(NTILE), dim3(512), 0, stream>>>(x, emb, Wtf, b1, b2, pool);
    head_kernel<<<dim3(1), dim3(128), 0, stream>>>(pool, wd1, bd1, wd2, bd2, out);
}

// Round 15
// 170.188 us; speedup vs baseline: 1.1589x; 1.0378x over previous
//
#include <hip/hip_runtime.h>

// ---------------- problem constants ----------------
#define BATCH   8
#define LSEQ    1048576          // 1<<20
#define KCONV   500
#define TWIN    2097             // (L-K)/K + 1
#define MROWS   16776            // BATCH*TWIN
#define KDIM    4000             // KCONV * C_IN
#define NDIM    256              // 2 * C_OUT
#define COUT    128
#define VOCAB   257
#define VOCABP  256              // padding row of emb (zeros)

#define BMR     80               // m-rows per block (5 x 16)
#define NTILE   210              // ceil(MROWS/80): fits 256 CUs, no serial tail
#define SLABP   20               // positions per slab = 160 k = 5 BK32 iters
#define NSLAB   25
#define NPAIR   12               // 12 pairs + 1 tail slab
#define NG      125              // total BK32 iterations
#define PLANE   (NDIM * 32)      // 8192 shorts per g-plane of Wtf
#define AROWSH  168              // padded shorts per A-slab row (160 + 8)
#define SLAB    (BMR * AROWSH)   // 13440 shorts per slab buffer
#define STAGEN  (BMR * SLABP)    // 1600 gathers per slab

// ---------------- ws layout (bytes) ----------------
#define WTF_OFF   0ull
#define WTF_BYTES ((size_t)NG * PLANE * 2)                  // 2,048,000
#define POOL_OFF  (WTF_OFF + WTF_BYTES)                     // 1024 floats

typedef __attribute__((ext_vector_type(8))) __bf16 bf16x8;
typedef __attribute__((ext_vector_type(4))) float  floatx4;

__device__ inline unsigned short f2bf(float f) {
    union { float f; unsigned u; } c; c.f = f;
    return (unsigned short)((c.u + 0x7FFFu + ((c.u >> 16) & 1u)) >> 16);
}
__device__ inline unsigned pack2(float lo, float hi) {
    return (unsigned)f2bf(lo) | ((unsigned)f2bf(hi) << 16);
}

// barrier that waits ONLY for LDS ops — leaves global (B/x prefetch) loads in flight
#define LDS_BARRIER() asm volatile("s_waitcnt lgkmcnt(0)\n\ts_barrier" ::: "memory")

// ---------------- kernel 1: frag-major weights + zero pool ----------------
// Wtf[g][n][kk] = w_n[e=(g*32+kk)&7][p=(g*32+kk)>>3]
__global__ __launch_bounds__(256) void wprep_kernel(const float* __restrict__ w1,
                                                    const float* __restrict__ w2,
                                                    unsigned short* __restrict__ Wtf,
                                                    float* __restrict__ pool) {
    const int n   = blockIdx.x;                        // 0..255
    const int tid = threadIdx.x;
    __shared__ float tile[KDIM];                       // 16 KB
    const float* src = (n < COUT) ? (w1 + (size_t)n * KDIM)
                                  : (w2 + (size_t)(n - COUT) * KDIM);
    for (int i = tid; i < KDIM; i += 256) tile[i] = src[i];
    __syncthreads();
    for (int i = tid; i < KDIM; i += 256) {
        int g = i >> 5, kk = i & 31;
        Wtf[(size_t)g * PLANE + n * 32 + kk] = f2bf(tile[(i & 7) * KCONV + (i >> 3)]);
    }
    if (n == 0 && tid < BATCH * COUT / 2)
        ((float2*)pool)[tid] = float2{0.f, 0.f};
}

// ---------------- kernel 2: fused embed + full-K GEMM + gate + max-pool ----------------
// r10 structure with QUAD-buffered As (gfx950 160KB LDS) and ONE barrier per
// 2 slabs (10 kt): 13 barriers instead of 25 — the direct test of the
// slab-boundary-bubble theory (the only untested variable left).
// Pair p: compute slabs 2p,2p+1 from As[(p&1)*2 + h]; then stage slabs
// 2p+2,2p+3 into the other half; LDS_BARRIER. Tail = slab 24 from As[0].
// Everything else identical to r10 (LDS emb table, B depth-2 register
// prefetch, lgkm-only barrier, x prefetched a pair ahead on vmcnt).
__global__ __launch_bounds__(512) void gemm_kernel(const int* __restrict__ x,
                                                   const float* __restrict__ emb,
                                                   const unsigned short* __restrict__ Wtf,
                                                   const float* __restrict__ b1,
                                                   const float* __restrict__ b2,
                                                   float* __restrict__ pool) {
    __shared__ unsigned short tableL[VOCAB * 8];       // 4112 B
    __shared__ unsigned short As[4][SLAB];             // 4 x 26.25 KB = 105 KB

    const int tid  = threadIdx.x;
    const int lane = tid & 63;
    const int wv   = tid >> 6;                         // 0..7
    const int m0   = blockIdx.x * BMR;
    const int r16  = lane & 15;
    const int q    = lane >> 4;                        // 0..3

    // ---- build bf16 emb table in LDS ----
    if (tid < VOCAB) {
        const float4* er = (const float4*)(emb + tid * 8);
        float4 a = er[0], b = er[1];
        uint4 u;
        u.x = pack2(a.x, a.y); u.y = pack2(a.z, a.w);
        u.z = pack2(b.x, b.y); u.w = pack2(b.z, b.w);
        *(uint4*)(tableL + tid * 8) = u;
    }

    // ---- staging roles: thread handles idx = tid + 512*l (idx < 1600) ----
    const int* xptr[4];
    int        loff[4];
    bool       sval[4];
#pragma unroll
    for (int l = 0; l < 4; ++l) {
        int idx = tid + 512 * l;
        sval[l] = (idx < STAGEN);
        int ic  = sval[l] ? idx : 0;
        int row = ic / SLABP;
        int pos = ic - row * SLABP;
        int am  = m0 + row;
        bool av = sval[l] && (am < MROWS);
        sval[l] = av;
        int amc = av ? am : 0;
        int b   = amc / TWIN;
        int t   = amc - b * TWIN;
        xptr[l] = x + ((size_t)b * LSEQ + (size_t)t * KCONV + pos);
        loff[l] = row * AROWSH + pos * 8;
    }

    // ---- compute role ----
    const int o = wv * 16 + r16;                       // 0..127
    const size_t boff0 = (size_t)o * 32 + q * 8;
    const size_t boff1 = (size_t)(o + 128) * 32 + q * 8;

    floatx4 acc[5][2];
#pragma unroll
    for (int i = 0; i < 5; ++i) { acc[i][0] = floatx4{0,0,0,0}; acc[i][1] = floatx4{0,0,0,0}; }

    bf16x8 bc0[2], bc1[2], bc2[2] = {};

    // staging helper (lambda): gather staged x-values through tableL into dst
    auto stage = [&](unsigned short* dst, const int* xs) {
#pragma unroll
        for (int l = 0; l < 4; ++l) {
            if (l == 3 && tid >= STAGEN - 3 * 512) break;
            uint4 g = *(const uint4*)(tableL + xs[l] * 8);
            *(uint4*)(dst + loff[l]) = g;
        }
    };
    // compute helper: 5 BK=32 iterations of slab s from Asb; B depth-2 pipeline
    auto compute_slab = [&](const unsigned short* Asb, int s) {
#pragma unroll
        for (int kt = 0; kt < 5; ++kt) {
            const int g = s * 5 + kt;
            if (g + 2 < NG) {
                const unsigned short* Wp = Wtf + (size_t)(g + 2) * PLANE;
                bc2[0] = *(const bf16x8*)(Wp + boff0);
                bc2[1] = *(const bf16x8*)(Wp + boff1);
            }
            bf16x8 af[5];
#pragma unroll
            for (int i = 0; i < 5; ++i)
                af[i] = *(const bf16x8*)(Asb + (i * 16 + r16) * AROWSH + (kt * 4 + q) * 8);
#pragma unroll
            for (int i = 0; i < 5; ++i) {
                acc[i][0] = __builtin_amdgcn_mfma_f32_16x16x32_bf16(af[i], bc0[0], acc[i][0], 0, 0, 0);
                acc[i][1] = __builtin_amdgcn_mfma_f32_16x16x32_bf16(af[i], bc0[1], acc[i][1], 0, 0, 0);
            }
            bc0[0] = bc1[0]; bc0[1] = bc1[1];
            bc1[0] = bc2[0]; bc1[1] = bc2[1];
        }
    };

    // ---- prologue: x for slabs 0,1 ----
    int xs0[4], xs1[4], xn0[4], xn1[4];
#pragma unroll
    for (int l = 0; l < 4; ++l) {
        xs0[l] = sval[l] ? xptr[l][0] : VOCABP;
        xs1[l] = sval[l] ? xptr[l][SLABP] : VOCABP;
    }
    __syncthreads();                                   // table visible

    // stage slabs 0,1 into As[0], As[1]; then x for slabs 2,3
    stage(&As[0][0], xs0);
    stage(&As[1][0], xs1);
#pragma unroll
    for (int l = 0; l < 4; ++l) {
        xs0[l] = sval[l] ? xptr[l][2 * SLABP] : VOCABP;
        xs1[l] = sval[l] ? xptr[l][3 * SLABP] : VOCABP;
    }
    LDS_BARRIER();

    // ---- B prefetch prologue: g=0,1 ----
    bc0[0] = *(const bf16x8*)(Wtf + boff0);
    bc0[1] = *(const bf16x8*)(Wtf + boff1);
    bc1[0] = *(const bf16x8*)(Wtf + PLANE + boff0);
    bc1[1] = *(const bf16x8*)(Wtf + PLANE + boff1);

    for (int p = 0; p < NPAIR; ++p) {
        const int s0 = 2 * p;
        // x loads for slabs 2p+4, 2p+5 (vmcnt; a full pair of cover)
        if (s0 + 4 < NSLAB) {
#pragma unroll
            for (int l = 0; l < 4; ++l) xn0[l] = sval[l] ? xptr[l][(s0 + 4) * SLABP] : VOCABP;
        }
        if (s0 + 5 < NSLAB) {
#pragma unroll
            for (int l = 0; l < 4; ++l) xn1[l] = sval[l] ? xptr[l][(s0 + 5) * SLABP] : VOCABP;
        }

        // ---- 10 uninterrupted kt from this pair's half ----
        const int half = (p & 1) * 2;
        compute_slab(&As[half][0],     s0);
        compute_slab(&As[half + 1][0], s0 + 1);

        // ---- stage next pair into the other half (drains into the barrier) ----
        const int oh = ((p & 1) ^ 1) * 2;
        if (s0 + 2 < NSLAB) stage(&As[oh][0],     xs0);
        if (s0 + 3 < NSLAB) stage(&As[oh + 1][0], xs1);
#pragma unroll
        for (int l = 0; l < 4; ++l) { xs0[l] = xn0[l]; xs1[l] = xn1[l]; }
        LDS_BARRIER();
    }
    // ---- tail: slab 24 from As[0] (staged by pair 11) ----
    compute_slab(&As[0][0], 24);

    // ---- epilogue: gate + per-batch max in registers, atomicMax flush ----
    // C/D layout: col = lane&15 (n), row = q*4 + reg (m).
    const float b1v = b1[o], b2v = b2[o];
    float cur = 0.0f;
    int curb  = (m0 + q * 4) / TWIN;
#pragma unroll
    for (int i = 0; i < 5; ++i) {
#pragma unroll
        for (int rg = 0; rg < 4; ++rg) {
            const int row = m0 + i * 16 + q * 4 + rg;
            if (row < MROWS) {
                const int bb = row / TWIN;
                if (bb != curb) {
                    atomicMax((int*)&pool[curb * COUT + o], __float_as_int(cur));
                    cur = 0.0f; curb = bb;
                }
                const float c1 = acc[i][0][rg] + b1v;
                const float c2 = acc[i][1][rg] + b2v;
                const float g  = fmaxf(c1, 0.0f) / (1.0f + __expf(-c2));
                cur = fmaxf(cur, g);
            }
        }
    }
    atomicMax((int*)&pool[curb * COUT + o], __float_as_int(cur));
}

// ---------------- kernel 3: dense head ----------------
__global__ __launch_bounds__(128) void head_kernel(const float* __restrict__ pool,
                                                   const float* __restrict__ wd1,
                                                   const float* __restrict__ bd1,
                                                   const float* __restrict__ wd2,
                                                   const float* __restrict__ bd2,
                                                   float* __restrict__ out) {
    __shared__ float red[BATCH][COUT];
    int j = threadIdx.x;                               // 0..127
    float wj = wd2[j];
#pragma unroll
    for (int b = 0; b < BATCH; ++b) {
        float s = bd1[j];
        for (int i = 0; i < COUT; ++i) s += pool[b * COUT + i] * wd1[j * COUT + i];
        red[b][j] = fmaxf(s, 0.0f) * wj;
    }
    __syncthreads();
    if (j < BATCH) {
        float s = 0.0f;
        for (int i = 0; i < COUT; ++i) s += red[j][i];
        out[j] = 1.0f / (1.0f + expf(-(s + bd2[0])));
    }
}

// ---------------- launch ----------------
extern "C" void kernel_launch(void* const* d_in, const int* in_sizes, int n_in,
                              void* d_out, int out_size, void* d_ws, size_t ws_size,
                              hipStream_t stream) {
    const int*   x   = (const int*)d_in[0];
    const float* emb = (const float*)d_in[1];
    const float* w1  = (const float*)d_in[2];
    const float* b1  = (const float*)d_in[3];
    const float* w2  = (const float*)d_in[4];
    const float* b2  = (const float*)d_in[5];
    const float* wd1 = (const float*)d_in[6];
    const float* bd1 = (const float*)d_in[7];
    const float* wd2 = (const float*)d_in[8];
    const float* bd2 = (const float*)d_in[9];
    float* out = (float*)d_out;

    unsigned short* Wtf  = (unsigned short*)((char*)d_ws + WTF_OFF);
    float*          pool = (float*)((char*)d_ws + POOL_OFF);

    wprep_kernel<<<dim3(NDIM), dim3(256), 0, stream>>>(w1, w2, Wtf, pool);
    gemm_kernel<<<dim3(NTILE), dim3(512), 0, stream>>>(x, emb, Wtf, b1, b2, pool);
    head_kernel<<<dim3(1), dim3(128), 0, stream>>>(pool, wd1, bd1, wd2, bd2, out);
}